// Round 3
// baseline (223.212 us; speedup 1.0000x reference)
//
#include <hip/hip_runtime.h>
#include <hip/hip_fp16.h>

// R16 DIAGNOSTIC: qc_apply has never appeared in rocprof top-5 (always
// below the 42us poison fills), so its VALUBusy / LDS_BANK_CONFLICT /
// Occupancy have never been observed, and the issue-count model (~11us)
// disagrees with measured (~38us) by 3.5x. This round launches three
// amplified variants to decompose the time:
//   V1 = DS skeleton : exact LDS state read/write pattern, no compute.
//   V2 = VALU skeleton: exact butterflies + f16 pack/unpack reg round
//        trips, no state LDS traffic.
//   V0 = real R15 kernel x REP (independent recomputes; last rep writes
//        the correct output). Launched last.
// All three are >44us so all land in top-5 WITH counters.

#define NQ 10
#define NL 5
#define NTH 64
#define REP 6

typedef float f2 __attribute__((ext_vector_type(2)));
typedef float f4 __attribute__((ext_vector_type(4)));
typedef unsigned int u32;

// ----- composed reversed ring-CNOT permutation (verified R3-R15), linear.
constexpr int csigma(int i) {
  for (int q = 0; q < NQ; ++q) {
    const int cb = 9 - q, tb = 9 - ((q + 1) % NQ);
    i ^= ((i >> cb) & 1) << tb;
  }
  return i;
}

constexpr int cA(int s) {
  return ((s ^ (s >> 4)) & 1) | ((((s >> 1) ^ (s >> 5)) & 1) << 1) |
         ((((s >> 2) ^ (s >> 6)) & 1) << 2) |
         ((((s >> 3) ^ (s >> 7)) & 1) << 3) |
         ((((s >> 4) ^ (s >> 8)) & 1) << 4) | (((s ^ (s >> 1)) & 1) << 5) |
         ((((s >> 1) ^ (s >> 2)) & 1) << 6) |
         ((((s >> 2) ^ (s >> 3)) & 1) << 7) | (((s >> 9) & 1) << 8);
}
constexpr int cC(int p) {
  return ((p >> 6) & 7) | (((p ^ (p >> 3)) & 1) << 3) |
         ((((p >> 1) ^ (p >> 4)) & 1) << 4) | (((p >> 2) & 1) << 5) |
         (((p >> 3) & 1) << 6) | (((p >> 4) & 1) << 7) | (((p >> 5) & 1) << 8);
}

__device__ __forceinline__ void pbfly(f2& aRe, f2& aIm, f2& bRe, f2& bIm,
                                      float h00, float h01x, float h01y,
                                      float h10x, float h10y, float h11x,
                                      float h11y) {
  const f2 naRe = h00 * aRe + h01x * bRe - h01y * bIm;
  const f2 naIm = h00 * aIm + h01x * bIm + h01y * bRe;
  const f2 nbRe = h10x * aRe - h10y * aIm + h11x * bRe - h11y * bIm;
  const f2 nbIm = h10x * aIm + h10y * aRe + h11x * bIm + h11y * bRe;
  aRe = naRe; aIm = naIm; bRe = nbRe; bIm = nbIm;
}

__device__ __forceinline__ u32 pk2(float a, float b) {
  __half2 h = __floats2half2_rn(a, b);
  return *(u32*)&h;
}
__device__ __forceinline__ f2 up2(u32 u) {
  __half2 h = *(__half2*)&u;
  return (f2){__low2float(h), __high2float(h)};
}

// V2 helper: emulate the inter-stage f16 pack->unpack cost in registers.
__device__ __forceinline__ void packrt(f2* vre, f2* vim) {
#pragma unroll
  for (int r = 0; r < 8; ++r) {
    const u32 a = pk2(vre[r].x, vre[r].y);
    const u32 b = pk2(vim[r].x, vim[r].y);
    const f2 fa = up2(a);
    const f2 fb = up2(b);
    vre[r] = fa;
    vim[r] = fb;
  }
}

template <int V>
__global__ __launch_bounds__(NTH) void qc_k(
    const float* __restrict__ x, const float* __restrict__ wts,
    float* __restrict__ out, int out_size) {
  __shared__ alignas(16) u32 sc[1024];
  __shared__ alignas(16) float sg[NL * NQ * 8];

  const int t = threadIdx.x;
  const int sv = blockIdx.x;

  // ---- gate build (not needed for the DS skeleton)
  if constexpr (V != 1) {
    if (t < NL * NQ) {
      const float th = wts[t * 3 + 0], ph = wts[t * 3 + 1], lm = wts[t * 3 + 2];
      const float ch_ = __cosf(0.5f * th), sh = __sinf(0.5f * th);
      const float cl = __cosf(lm), sl = __sinf(lm);
      const float cp = __cosf(ph), sp = __sinf(ph);
      const float cpl = __cosf(ph + lm), spl = __sinf(ph + lm);
      float* G = sg + t * 8;
      G[0] = ch_;       G[1] = 0.0f;
      G[2] = cp * sh;   G[3] = sp * sh;
      G[4] = -cl * sh;  G[5] = -sl * sh;
      G[6] = cpl * ch_; G[7] = spl * ch_;
    }
  }

  // ---- sigma(t) + address bases (identical to R15)
  int st = t;
#pragma unroll
  for (int q = 0; q < NQ; ++q) {
    const int cb = 9 - q, tb = 9 - ((q + 1) % NQ);
    st ^= ((st >> cb) & 1) << tb;
  }
  const int baseS = cA(st) << 1;
  const int tb1 = t << 1;
  const int tb2 = (((t & 7) | ((t >> 3) << 6)) ^ ((((t >> 3) & 3)) << 3)) << 1;
  const int tc2 = cC((t & 7) | ((t >> 3) << 6)) << 1;
  const int tc3 = cC(t << 3) << 1;
  const int ta3 = cA(t << 3) << 1;

  static constexpr int SRC[8] = {
      cA(csigma(0 << 6)) << 1, cA(csigma(1 << 6)) << 1, cA(csigma(2 << 6)) << 1,
      cA(csigma(3 << 6)) << 1, cA(csigma(4 << 6)) << 1, cA(csigma(5 << 6)) << 1,
      cA(csigma(6 << 6)) << 1, cA(csigma(7 << 6)) << 1};
#define CB1v(r) ((((r) << 6) ^ (((r) & 3) << 3)) << 1)
  static constexpr int CB1[8] = {CB1v(0), CB1v(1), CB1v(2), CB1v(3),
                                 CB1v(4), CB1v(5), CB1v(6), CB1v(7)};
  static constexpr int CC2[8] = {cC(0 << 3) << 1, cC(1 << 3) << 1,
                                 cC(2 << 3) << 1, cC(3 << 3) << 1,
                                 cC(4 << 3) << 1, cC(5 << 3) << 1,
                                 cC(6 << 3) << 1, cC(7 << 3) << 1};
  static constexpr int CC3[8] = {cC(0) << 1, cC(1) << 1, cC(2) << 1,
                                 cC(3) << 1, cC(4) << 1, cC(5) << 1,
                                 cC(6) << 1, cC(7) << 1};
  static constexpr int CWA[8] = {
      (cA(0) << 1) | 0, (cA(1) << 1) | 1, (cA(2) << 1) | 0, (cA(3) << 1) | 1,
      (cA(4) << 1) | 0, (cA(5) << 1) | 1, (cA(6) << 1) | 0, (cA(7) << 1) | 1};
  static constexpr int CAj[16] = {cA(0),  cA(1),  cA(2),  cA(3),
                                  cA(4),  cA(5),  cA(6),  cA(7),
                                  cA(8),  cA(9),  cA(10), cA(11),
                                  cA(12), cA(13), cA(14), cA(15)};

  float acc = 0.0f;  // V2 keepalive accumulator

#pragma unroll 1
  for (int rep = 0; rep < REP; ++rep) {
    // ---- init (state into LDS for V0/V1; straight into regs for V2)
    if constexpr (V != 2) {
      const float* xs = x + (size_t)sv * 1024;
      float4 xv[4];
#pragma unroll
      for (int i4 = 0; i4 < 4; ++i4) xv[i4] = ((const float4*)xs)[4 * t + i4];
      const int ib2 = cA(16 * t) << 1;
      const int ihb = (t >> 5) & 1;
#pragma unroll
      for (int j = 0; j < 16; ++j) {
        const float xj = ((const float*)xv)[j];
        const int word = (ib2 ^ (CAj[j] << 1)) | (ihb ^ (j & 1));
        sc[word] = pk2(xj, 0.0f);
      }
    }

    f2 vre[8], vim[8];
    if constexpr (V == 2) {
      const float* xs = x + (size_t)sv * 1024;
      float4 xv[4];
#pragma unroll
      for (int i4 = 0; i4 < 4; ++i4) xv[i4] = ((const float4*)xs)[4 * t + i4];
      const float* f = (const float*)xv;
#pragma unroll
      for (int r = 0; r < 8; ++r) {
        vre[r] = (f2){f[2 * r], f[2 * r + 1]};
        vim[r] = (f2){f[2 * r + 1], f[2 * r]};  // nonzero: no const-folding
      }
    }

    for (int l = NL - 1; l >= 0; --l) {
      if constexpr (V == 1) {
        // ======== DS skeleton: same reads/writes, value passthrough.
        uint2 bb[8];
#pragma unroll
        for (int r = 0; r < 8; ++r) bb[r] = *(const uint2*)&sc[baseS ^ SRC[r]];
#pragma unroll
        for (int r = 0; r < 8; ++r) *(uint2*)&sc[tb1 ^ CB1[r]] = bb[r];
#pragma unroll
        for (int r = 0; r < 8; ++r) bb[r] = *(const uint2*)&sc[tb2 ^ (r << 4)];
#pragma unroll
        for (int r = 0; r < 8; ++r) *(uint2*)&sc[tc2 ^ CC2[r]] = bb[r];
#pragma unroll
        for (int r = 0; r < 8; ++r) bb[r] = *(const uint2*)&sc[tc3 ^ CC3[r]];
#pragma unroll
        for (int r = 0; r < 8; ++r) {
          const int w0 = ta3 ^ CWA[r];
          sc[w0] = bb[r].x;
          sc[w0 ^ 513] = bb[r].y;
        }
      } else {
        const float* gl = sg + l * NQ * 8;

        // ======== RT1
        if constexpr (V == 0) {
#pragma unroll
          for (int r = 0; r < 8; ++r) {
            const uint2 b = *(const uint2*)&sc[baseS ^ SRC[r]];
            const f2 lo = up2(b.x);
            const f2 hi = up2(b.y);
            vre[r] = (f2){lo.x, hi.x};
            vim[r] = (f2){lo.y, hi.y};
          }
        }
        {
          const int qb[3] = {3, 2, 1};
#pragma unroll
          for (int e = 0; e < 3; ++e) {
            const float* G = gl + qb[e] * 8;
            const f4 ga = *(const f4*)&G[0];
            const f4 gb = *(const f4*)&G[4];
            const int m = 1 << e;
#pragma unroll
            for (int r = 0; r < 8; ++r)
              if (!(r & m))
                pbfly(vre[r], vim[r], vre[r | m], vim[r | m], ga.x, ga.z, ga.w,
                      gb.x, gb.y, gb.z, gb.w);
          }
        }
        if constexpr (V == 0) {
#pragma unroll
          for (int r = 0; r < 8; ++r) {
            uint2 b;
            b.x = pk2(vre[r].x, vre[r].y);
            b.y = pk2(vim[r].x, vim[r].y);
            *(uint2*)&sc[tb1 ^ CB1[r]] = b;
          }
        } else {
          packrt(vre, vim);
        }

        // ======== RT2
        if constexpr (V == 0) {
#pragma unroll
          for (int r = 0; r < 8; ++r) {
            const uint2 b = *(const uint2*)&sc[tb2 ^ (r << 4)];
            vre[r] = up2(b.x);
            vim[r] = up2(b.y);
          }
        }
        {
          const int qb[3] = {6, 5, 4};
#pragma unroll
          for (int e = 0; e < 3; ++e) {
            const float* G = gl + qb[e] * 8;
            const f4 ga = *(const f4*)&G[0];
            const f4 gb = *(const f4*)&G[4];
            const int m = 1 << e;
#pragma unroll
            for (int r = 0; r < 8; ++r)
              if (!(r & m))
                pbfly(vre[r], vim[r], vre[r | m], vim[r | m], ga.x, ga.z, ga.w,
                      gb.x, gb.y, gb.z, gb.w);
          }
        }
        if constexpr (V == 0) {
#pragma unroll
          for (int r = 0; r < 8; ++r) {
            uint2 b;
            b.x = pk2(vre[r].x, vre[r].y);
            b.y = pk2(vim[r].x, vim[r].y);
            *(uint2*)&sc[tc2 ^ CC2[r]] = b;
          }
        } else {
          packrt(vre, vim);
        }

        // ======== RT3
        if constexpr (V == 0) {
#pragma unroll
          for (int r = 0; r < 8; ++r) {
            const uint2 b = *(const uint2*)&sc[tc3 ^ CC3[r]];
            vre[r] = up2(b.x);
            vim[r] = up2(b.y);
          }
        }
        {
          const int qb[3] = {9, 8, 7};
#pragma unroll
          for (int e = 0; e < 3; ++e) {
            const float* G = gl + qb[e] * 8;
            const f4 ga = *(const f4*)&G[0];
            const f4 gb = *(const f4*)&G[4];
            const int m = 1 << e;
#pragma unroll
            for (int r = 0; r < 8; ++r)
              if (!(r & m))
                pbfly(vre[r], vim[r], vre[r | m], vim[r | m], ga.x, ga.z, ga.w,
                      gb.x, gb.y, gb.z, gb.w);
          }
        }
        {  // qubit-0 on SV bit 9 (pack halves)
          const f4 ga = *(const f4*)&gl[0];
          const f4 gb = *(const f4*)&gl[4];
          const float h00 = ga.x, h01x = ga.z, h01y = ga.w, h10x = gb.x,
                      h10y = gb.y, h11x = gb.z, h11y = gb.w;
#pragma unroll
          for (int r = 0; r < 8; ++r) {
            const float re0 = vre[r].x, im0 = vim[r].x;
            const float re1 = vre[r].y, im1 = vim[r].y;
            vre[r].x = h00 * re0 + h01x * re1 - h01y * im1;
            vre[r].y = h10x * re0 - h10y * im0 + h11x * re1 - h11y * im1;
            if (l != 0) {
              vim[r].x = h00 * im0 + h01x * im1 + h01y * re1;
              vim[r].y = h10x * im0 + h10y * re0 + h11x * im1 + h11y * re1;
            }
          }
        }
        if (l != 0) {
          if constexpr (V == 0) {
#pragma unroll
            for (int r = 0; r < 8; ++r) {
              const int w0 = ta3 ^ CWA[r];
              sc[w0] = pk2(vre[r].x, vim[r].x);
              sc[w0 ^ 513] = pk2(vre[r].y, vim[r].y);
            }
          } else {
            packrt(vre, vim);
          }
        }
      }
    }

    if constexpr (V == 2) {
#pragma unroll
      for (int r = 0; r < 8; ++r) acc += vre[r].x + vre[r].y;
    }
    if constexpr (V == 0) {
      if (rep == REP - 1) {
        const size_t ob = (size_t)sv * 1024 + 8 * t;
        if (ob + 8 <= (size_t)out_size) {
          *(float4*)(out + ob) =
              make_float4(vre[0].x, vre[1].x, vre[2].x, vre[3].x);
          *(float4*)(out + ob + 4) =
              make_float4(vre[4].x, vre[5].x, vre[6].x, vre[7].x);
        }
        if (ob + 512 + 8 <= (size_t)out_size) {
          *(float4*)(out + ob + 512) =
              make_float4(vre[0].y, vre[1].y, vre[2].y, vre[3].y);
          *(float4*)(out + ob + 516) =
              make_float4(vre[4].y, vre[5].y, vre[6].y, vre[7].y);
        }
      }
    }
  }

  if constexpr (V == 1) {
    // Anchor: may-alias read keeps the whole LDS store chain live (anti-DSE).
    const u32 z = sc[t] ^ sc[t + 512];
    asm volatile("" ::"v"(z));
  }
  if constexpr (V == 2) {
    asm volatile("" ::"v"(acc));
  }
}

extern "C" void kernel_launch(void* const* d_in, const int* in_sizes, int n_in,
                              void* d_out, int out_size, void* d_ws,
                              size_t ws_size, hipStream_t stream) {
  const float* x = (const float*)d_in[0];   // [128,16,32,32] f32
  const float* w = (const float*)d_in[1];   // [5,10,3] f32
  float* out = (float*)d_out;               // f32 (real part of complex64)
  const int nstates = in_sizes[0] / 1024;   // 2048
  // Diagnostics first (touch nothing global), real kernel last.
  qc_k<1><<<nstates, NTH, 0, stream>>>(x, w, out, out_size);
  qc_k<2><<<nstates, NTH, 0, stream>>>(x, w, out, out_size);
  qc_k<0><<<nstates, NTH, 0, stream>>>(x, w, out, out_size);
}

// Round 5
// 81.413 us; speedup vs baseline: 2.7417x; 2.7417x over previous
//
#include <hip/hip_runtime.h>
#include <hip/hip_fp16.h>

// out[s,i] = Re( U x_s ), reverse-order transposed-gate statevector sim.
// R18 = R17 resubmitted verbatim (R17's bench failed on container acquire,
// not on the kernel: no compile/test/timeout fault; kernel has no barriers,
// no inter-wave dependencies, 22.8KB LDS, grid 512 -- nothing hang-capable).
// R17 = R15 repacked as 4 SVs per 256-thread block (4 independent waves,
// private LDS state + private gate table per wave, ZERO barriers).
// Per-wave code/addresses/f16-state are bit-identical to R15; only the
// launch granularity changes: 2048 x 64-thr wgs -> 512 x 256-thr wgs.
// Rationale (R16 ablation): DS-only, VALU-only and full kernels all time
// identically; ~30us of the 38us dispatch is variant-independent overhead.
// This A/Bs the wg-launch-granularity mechanism (the only one fixable
// in-kernel) while leaving marginal work untouched.

#define NQ 10
#define NL 5
#define NTH 256
#define SVPB 4   // statevectors (waves) per block

typedef float f2 __attribute__((ext_vector_type(2)));
typedef float f4 __attribute__((ext_vector_type(4)));
typedef unsigned int u32;

// ----- composed reversed ring-CNOT permutation (verified R3-R15), linear.
constexpr int csigma(int i) {
  for (int q = 0; q < NQ; ++q) {
    const int cb = 9 - q, tb = 9 - ((q + 1) % NQ);
    i ^= ((i >> cb) & 1) << tb;
  }
  return i;
}

constexpr int cA(int s) {
  return ((s ^ (s >> 4)) & 1) | ((((s >> 1) ^ (s >> 5)) & 1) << 1) |
         ((((s >> 2) ^ (s >> 6)) & 1) << 2) |
         ((((s >> 3) ^ (s >> 7)) & 1) << 3) |
         ((((s >> 4) ^ (s >> 8)) & 1) << 4) | (((s ^ (s >> 1)) & 1) << 5) |
         ((((s >> 1) ^ (s >> 2)) & 1) << 6) |
         ((((s >> 2) ^ (s >> 3)) & 1) << 7) | (((s >> 9) & 1) << 8);
}
constexpr int cC(int p) {
  return ((p >> 6) & 7) | (((p ^ (p >> 3)) & 1) << 3) |
         ((((p >> 1) ^ (p >> 4)) & 1) << 4) | (((p >> 2) & 1) << 5) |
         (((p >> 3) & 1) << 6) | (((p >> 4) & 1) << 7) | (((p >> 5) & 1) << 8);
}

__device__ __forceinline__ void pbfly(f2& aRe, f2& aIm, f2& bRe, f2& bIm,
                                      float h00, float h01x, float h01y,
                                      float h10x, float h10y, float h11x,
                                      float h11y) {
  const f2 naRe = h00 * aRe + h01x * bRe - h01y * bIm;
  const f2 naIm = h00 * aIm + h01x * bIm + h01y * bRe;
  const f2 nbRe = h10x * aRe - h10y * aIm + h11x * bRe - h11y * bIm;
  const f2 nbIm = h10x * aIm + h10y * aRe + h11x * bIm + h11y * bRe;
  aRe = naRe; aIm = naIm; bRe = nbRe; bIm = nbIm;
}

__device__ __forceinline__ u32 pk2(float a, float b) {
  __half2 h = __floats2half2_rn(a, b);
  return *(u32*)&h;
}
__device__ __forceinline__ f2 up2(u32 u) {
  __half2 h = *(__half2*)&u;
  return (f2){__low2float(h), __high2float(h)};
}

__global__ __launch_bounds__(NTH) void qc_apply(
    const float* __restrict__ x, const float* __restrict__ wts,
    float* __restrict__ out, int out_size) {
  // Per-wave private regions: 1024 u32 state words + 400 f32 gate floats.
  // 4096 B state stride keeps bank alignment identical to R15 per wave.
  __shared__ alignas(16) u32 scw[SVPB][1024];
  __shared__ alignas(16) float sgw[SVPB][NL * NQ * 8];

  const int tid = threadIdx.x;
  const int w = tid >> 6;        // wave id within block = SV selector
  const int t = tid & 63;        // lane (was threadIdx.x in R15)
  const int sv = blockIdx.x * SVPB + w;

  u32* sc = scw[w];
  float* sg = sgw[w];

  // ---- in-kernel gate build (lanes < 50 of EACH wave): transposed U3.
  // Same-wave DS ordering -> no barrier needed (validated R12-R15).
  if (t < NL * NQ) {
    const float th = wts[t * 3 + 0], ph = wts[t * 3 + 1], lm = wts[t * 3 + 2];
    const float ch_ = __cosf(0.5f * th), sh = __sinf(0.5f * th);
    const float cl = __cosf(lm), sl = __sinf(lm);
    const float cp = __cosf(ph), sp = __sinf(ph);
    const float cpl = __cosf(ph + lm), spl = __sinf(ph + lm);
    float* G = sg + t * 8;
    G[0] = ch_;       G[1] = 0.0f;
    G[2] = cp * sh;   G[3] = sp * sh;
    G[4] = -cl * sh;  G[5] = -sl * sh;
    G[6] = cpl * ch_; G[7] = spl * ch_;
  }

  // ---- runtime sigma(t) and hoisted address bases (identical to R15).
  int st = t;
#pragma unroll
  for (int q = 0; q < NQ; ++q) {
    const int cb = 9 - q, tb = 9 - ((q + 1) % NQ);
    st ^= ((st >> cb) & 1) << tb;
  }
  const int baseS = cA(st) << 1;                 // sigma-read base (layout A)
  const int tb1 = t << 1;                        // RT1-write base (layout B)
  const int tb2 = (((t & 7) | ((t >> 3) << 6)) ^ ((((t >> 3) & 3)) << 3)) << 1;
  const int tc2 = cC((t & 7) | ((t >> 3) << 6)) << 1;  // RT2-write base (C)
  const int tc3 = cC(t << 3) << 1;               // RT3-read base (C)
  const int ta3 = cA(t << 3) << 1;               // RT3-write base (A)

  static constexpr int SRC[8] = {
      cA(csigma(0 << 6)) << 1, cA(csigma(1 << 6)) << 1, cA(csigma(2 << 6)) << 1,
      cA(csigma(3 << 6)) << 1, cA(csigma(4 << 6)) << 1, cA(csigma(5 << 6)) << 1,
      cA(csigma(6 << 6)) << 1, cA(csigma(7 << 6)) << 1};
#define CB1v(r) ((((r) << 6) ^ (((r) & 3) << 3)) << 1)
  static constexpr int CB1[8] = {CB1v(0), CB1v(1), CB1v(2), CB1v(3),
                                 CB1v(4), CB1v(5), CB1v(6), CB1v(7)};
  static constexpr int CC2[8] = {cC(0 << 3) << 1, cC(1 << 3) << 1,
                                 cC(2 << 3) << 1, cC(3 << 3) << 1,
                                 cC(4 << 3) << 1, cC(5 << 3) << 1,
                                 cC(6 << 3) << 1, cC(7 << 3) << 1};
  static constexpr int CC3[8] = {cC(0) << 1, cC(1) << 1, cC(2) << 1,
                                 cC(3) << 1, cC(4) << 1, cC(5) << 1,
                                 cC(6) << 1, cC(7) << 1};
  static constexpr int CWA[8] = {
      (cA(0) << 1) | 0, (cA(1) << 1) | 1, (cA(2) << 1) | 0, (cA(3) << 1) | 1,
      (cA(4) << 1) | 0, (cA(5) << 1) | 1, (cA(6) << 1) | 0, (cA(7) << 1) | 1};
  static constexpr int CAj[16] = {cA(0),  cA(1),  cA(2),  cA(3),
                                  cA(4),  cA(5),  cA(6),  cA(7),
                                  cA(8),  cA(9),  cA(10), cA(11),
                                  cA(12), cA(13), cA(14), cA(15)};

  // ---- init: x real -> layout A f16 (state s at word 2*A(s)+h(s), h=s0^s9).
  {
    const float* xs = x + (size_t)sv * 1024;
    float4 xv[4];
#pragma unroll
    for (int i4 = 0; i4 < 4; ++i4) xv[i4] = ((const float4*)xs)[4 * t + i4];
    const int ib2 = cA(16 * t) << 1;
    const int ihb = (t >> 5) & 1;  // h(16t) = s9 = t5
#pragma unroll
    for (int j = 0; j < 16; ++j) {
      const float xj = ((const float*)xv)[j];
      const int word = (ib2 ^ (CAj[j] << 1)) | (ihb ^ (j & 1));
      sc[word] = pk2(xj, 0.0f);
    }
  }

  f2 vre[8], vim[8];

  for (int l = NL - 1; l >= 0; --l) {
    const float* gl = sg + l * NQ * 8;   // LDS pointer: uniform ds_read bcast

    // ======== RT1: sigma-gather (layout A); reg bits = SV bits 6-8.
#pragma unroll
    for (int r = 0; r < 8; ++r) {
      const uint2 b = *(const uint2*)&sc[baseS ^ SRC[r]];
      const f2 lo = up2(b.x);
      const f2 hi = up2(b.y);
      vre[r] = (f2){lo.x, hi.x};
      vim[r] = (f2){lo.y, hi.y};
    }
    {
      const int qb[3] = {3, 2, 1};  // reg bit e = SV bit 6+e <-> qubit 3-e
#pragma unroll
      for (int e = 0; e < 3; ++e) {
        const float* G = gl + qb[e] * 8;
        const f4 ga = *(const f4*)&G[0];
        const f4 gb = *(const f4*)&G[4];
        const int m = 1 << e;
#pragma unroll
        for (int r = 0; r < 8; ++r)
          if (!(r & m))
            pbfly(vre[r], vim[r], vre[r | m], vim[r | m], ga.x, ga.z, ga.w,
                  gb.x, gb.y, gb.z, gb.w);
      }
    }
#pragma unroll
    for (int r = 0; r < 8; ++r) {
      uint2 b;
      b.x = pk2(vre[r].x, vre[r].y);
      b.y = pk2(vim[r].x, vim[r].y);
      *(uint2*)&sc[tb1 ^ CB1[r]] = b;
    }

    // ======== RT2 (layout B -> C); reg bits = SV bits 3-5.
#pragma unroll
    for (int r = 0; r < 8; ++r) {
      const uint2 b = *(const uint2*)&sc[tb2 ^ (r << 4)];
      vre[r] = up2(b.x);
      vim[r] = up2(b.y);
    }
    {
      const int qb[3] = {6, 5, 4};  // reg bit e = SV bit 3+e <-> qubit 6-e
#pragma unroll
      for (int e = 0; e < 3; ++e) {
        const float* G = gl + qb[e] * 8;
        const f4 ga = *(const f4*)&G[0];
        const f4 gb = *(const f4*)&G[4];
        const int m = 1 << e;
#pragma unroll
        for (int r = 0; r < 8; ++r)
          if (!(r & m))
            pbfly(vre[r], vim[r], vre[r | m], vim[r | m], ga.x, ga.z, ga.w,
                  gb.x, gb.y, gb.z, gb.w);
      }
    }
#pragma unroll
    for (int r = 0; r < 8; ++r) {
      uint2 b;
      b.x = pk2(vre[r].x, vre[r].y);
      b.y = pk2(vim[r].x, vim[r].y);
      *(uint2*)&sc[tc2 ^ CC2[r]] = b;
    }

    // ======== RT3 (layout C); reg bits = SV bits 0-2, + bit-9 gate.
#pragma unroll
    for (int r = 0; r < 8; ++r) {
      const uint2 b = *(const uint2*)&sc[tc3 ^ CC3[r]];
      vre[r] = up2(b.x);
      vim[r] = up2(b.y);
    }
    {
      const int qb[3] = {9, 8, 7};  // reg bit e = SV bit e <-> qubit 9-e
#pragma unroll
      for (int e = 0; e < 3; ++e) {
        const float* G = gl + qb[e] * 8;
        const f4 ga = *(const f4*)&G[0];
        const f4 gb = *(const f4*)&G[4];
        const int m = 1 << e;
#pragma unroll
        for (int r = 0; r < 8; ++r)
          if (!(r & m))
            pbfly(vre[r], vim[r], vre[r | m], vim[r | m], ga.x, ga.z, ga.w,
                  gb.x, gb.y, gb.z, gb.w);
      }
    }
    {  // qubit-0 gate on SV bit 9 = pack halves (.x <-> .y), scalar form.
      const f4 ga = *(const f4*)&gl[0];
      const f4 gb = *(const f4*)&gl[4];
      const float h00 = ga.x, h01x = ga.z, h01y = ga.w, h10x = gb.x,
                  h10y = gb.y, h11x = gb.z, h11y = gb.w;
#pragma unroll
      for (int r = 0; r < 8; ++r) {
        const float re0 = vre[r].x, im0 = vim[r].x;
        const float re1 = vre[r].y, im1 = vim[r].y;
        vre[r].x = h00 * re0 + h01x * re1 - h01y * im1;
        vre[r].y = h10x * re0 - h10y * im0 + h11x * re1 - h11y * im1;
        if (l != 0) {  // vim dead in the final layer (out = Re only)
          vim[r].x = h00 * im0 + h01x * im1 + h01y * re1;
          vim[r].y = h10x * im0 + h10y * re0 + h11x * im1 + h11y * re1;
        }
      }
    }
    if (l != 0) {
#pragma unroll
      for (int r = 0; r < 8; ++r) {
        const int w0 = ta3 ^ CWA[r];
        sc[w0] = pk2(vre[r].x, vim[r].x);
        sc[w0 ^ 513] = pk2(vre[r].y, vim[r].y);
      }
    }
  }

  // ---- output: reals only. .x -> indices 8t..8t+7, .y -> +512.
  const size_t ob = (size_t)sv * 1024 + 8 * t;
  if (ob + 8 <= (size_t)out_size) {
    *(float4*)(out + ob) = make_float4(vre[0].x, vre[1].x, vre[2].x, vre[3].x);
    *(float4*)(out + ob + 4) =
        make_float4(vre[4].x, vre[5].x, vre[6].x, vre[7].x);
  }
  if (ob + 512 + 8 <= (size_t)out_size) {
    *(float4*)(out + ob + 512) =
        make_float4(vre[0].y, vre[1].y, vre[2].y, vre[3].y);
    *(float4*)(out + ob + 516) =
        make_float4(vre[4].y, vre[5].y, vre[6].y, vre[7].y);
  }
}

extern "C" void kernel_launch(void* const* d_in, const int* in_sizes, int n_in,
                              void* d_out, int out_size, void* d_ws,
                              size_t ws_size, hipStream_t stream) {
  const float* x = (const float*)d_in[0];   // [128,16,32,32] f32
  const float* w = (const float*)d_in[1];   // [5,10,3] f32
  float* out = (float*)d_out;               // f32 (real part of complex64)
  const int nstates = in_sizes[0] / 1024;   // 2048
  qc_apply<<<nstates / SVPB, NTH, 0, stream>>>(x, w, out, out_size);
}